// Round 9
// baseline (157.415 us; speedup 1.0000x reference)
//
#include <hip/hip_runtime.h>

#define NUM_CLS   131072
#define NUM_NODE  70
#define DRUG_NUM  38
#define NSEG      140
#define ROWLEN    70
#define FEA       128
#define MTOT      524288
#define BATCH     8192
#define NB_H      512                 // histogram / scatter blocks (1024 entries each)
#define NCHUNK    64                  // accumulate chunks per segment

typedef __attribute__((ext_vector_type(8))) short bfrag;
typedef __attribute__((ext_vector_type(4))) float f32x4;

__device__ __forceinline__ unsigned short f2bf_rtne(float x) {
  unsigned int u = __float_as_uint(x);
  u = (u + 0x7fffu + ((u >> 16) & 1u)) >> 16;
  return (unsigned short)u;
}
__device__ __forceinline__ float bf2f(unsigned short h) {
  return __uint_as_float((unsigned int)h << 16);
}
#define MFMA16(a, b, c) __builtin_amdgcn_mfma_f32_16x16x32_bf16((a), (b), (c), 0, 0, 0)

// ---------------- P1: per-block segment histogram ----------------
__global__ __launch_bounds__(256) void hist_k(
    const int* __restrict__ he_node, const int* __restrict__ he_edge,
    int* __restrict__ hist_t)        // [NSEG][NB_H]
{
  __shared__ int h[NSEG];
  const int tid = threadIdx.x;
  if (tid < NSEG) h[tid] = 0;
  __syncthreads();
  const int base = blockIdx.x * 1024;
  #pragma unroll
  for (int t = 0; t < 4; ++t) {
    const int e = base + t * 256 + tid;
    const int seg = he_node[e] * 2 + (he_edge[e] >= NUM_CLS);
    atomicAdd(&h[seg], 1);
  }
  __syncthreads();
  if (tid < NSEG) hist_t[tid * NB_H + blockIdx.x] = h[tid];
}

// ---------------- P2a: per-seg exclusive scan over blocks ----------------
__global__ __launch_bounds__(512) void scan_blocks_k(
    const int* __restrict__ hist_t, int* __restrict__ scan_t,
    int* __restrict__ seg_total)
{
  __shared__ int v[NB_H];
  const int s = blockIdx.x, tid = threadIdx.x;
  const int x0 = hist_t[s * NB_H + tid];
  v[tid] = x0;
  __syncthreads();
  for (int off = 1; off < NB_H; off <<= 1) {
    int y = (tid >= off) ? v[tid - off] : 0;
    __syncthreads();
    v[tid] += y;
    __syncthreads();
  }
  scan_t[s * NB_H + tid] = v[tid] - x0;     // exclusive
  if (tid == NB_H - 1) seg_total[s] = v[tid];
}

// ---------------- P2b: segment bases ----------------
__global__ __launch_bounds__(256) void base_k(
    const int* __restrict__ seg_total, int* __restrict__ seg_base,
    float* __restrict__ cnt_f)
{
  __shared__ int tot[NSEG];
  __shared__ int bs[NSEG + 1];
  const int tid = threadIdx.x;
  if (tid < NSEG) tot[tid] = seg_total[tid];
  __syncthreads();
  if (tid == 0) {
    int run = 0;
    for (int s = 0; s < NSEG; ++s) { bs[s] = run; run += tot[s]; }
    bs[NSEG] = run;
  }
  __syncthreads();
  if (tid < NSEG) { seg_base[tid] = bs[tid]; cnt_f[tid] = (float)tot[tid]; }
  if (tid == NSEG) seg_base[NSEG] = bs[NSEG];
}

// ---------------- P3: scatter row-offsets into seg-sorted order ----------------
__global__ __launch_bounds__(256) void scatter_k(
    const int* __restrict__ he_node, const int* __restrict__ he_edge,
    const int* __restrict__ scan_t, const int* __restrict__ seg_base,
    int* __restrict__ sorted_off)
{
  __shared__ int rank[NSEG];
  __shared__ int base[NSEG];
  const int tid = threadIdx.x;
  if (tid < NSEG) {
    rank[tid] = 0;
    base[tid] = seg_base[tid] + scan_t[tid * NB_H + blockIdx.x];
  }
  __syncthreads();
  const int e0 = blockIdx.x * 1024;
  #pragma unroll
  for (int t = 0; t < 4; ++t) {
    const int e = e0 + t * 256 + tid;
    const int node = he_node[e];
    const int edge = he_edge[e];
    const int isdc = (edge >= NUM_CLS);
    const int seg  = node * 2 + isdc;
    const int off  = (isdc ? edge - NUM_CLS : edge) * ROWLEN;
    const int r = atomicAdd(&rank[seg], 1);
    sorted_off[base[seg] + r] = off;
  }
}

// ---------------- P4: wave-per-entry accumulate; lane l owns cols l, 64+l ----
__global__ __launch_bounds__(256) void seg_acc_k(
    const float* __restrict__ dth_cls, const float* __restrict__ dth_dc,
    const int* __restrict__ sorted_off, const int* __restrict__ seg_base,
    float* __restrict__ partial)     // [NSEG][NCHUNK][ROWLEN]
{
  const int s = blockIdx.x;
  const int wid = threadIdx.x >> 6, lane = threadIdx.x & 63;
  const int chunk = blockIdx.y * 4 + wid;       // gridDim.y = NCHUNK/4
  const int b0 = seg_base[s];
  const int n  = seg_base[s + 1] - b0;
  const int c0 = b0 + (int)(((long long)n * chunk) >> 6);
  const int c1 = b0 + (int)(((long long)n * (chunk + 1)) >> 6);
  const float* __restrict__ T = (s & 1) ? dth_dc : dth_cls;
  const bool tail = (lane < ROWLEN - 64);

  float accm = 0.f, acct = 0.f;
  int i = c0;
  for (; i + 8 <= c1; i += 8) {
    int o[8];
    #pragma unroll
    for (int u = 0; u < 8; ++u) o[u] = sorted_off[i + u];   // wave-uniform s_loads
    float v[8];
    #pragma unroll
    for (int u = 0; u < 8; ++u) v[u] = T[o[u] + lane];
    float t[8];
    #pragma unroll
    for (int u = 0; u < 8; ++u) t[u] = tail ? T[o[u] + 64 + lane] : 0.f;
    #pragma unroll
    for (int u = 0; u < 8; ++u) { accm += v[u]; acct += t[u]; }
  }
  for (; i < c1; ++i) {
    const int o = sorted_off[i];
    accm += T[o + lane];
    if (tail) acct += T[o + 64 + lane];
  }

  float* dst = partial + ((size_t)s * NCHUNK + chunk) * ROWLEN;
  dst[lane] = accm;
  if (tail) dst[64 + lane] = acct;
}

// ---------------- P5+K3a fused: rowsum reduce + edge_group GEMV ----------------
__global__ __launch_bounds__(128) void seg_fin_edge_k(
    const float* __restrict__ partial, const float* __restrict__ cnt,
    const float* __restrict__ dE, const float* __restrict__ cE,
    float* __restrict__ edge_group)
{
  __shared__ float rs[ROWLEN];
  const int s = blockIdx.x, c = threadIdx.x;
  if (c < ROWLEN) {
    float v = 0.f;
    const float* p = partial + (size_t)s * NCHUNK * ROWLEN + c;
    #pragma unroll 8
    for (int k = 0; k < NCHUNK; ++k) v += p[k * ROWLEN];
    rs[c] = v;
  }
  __syncthreads();
  float a = 0.f;
  #pragma unroll
  for (int k = 0; k < DRUG_NUM; ++k) a += rs[k] * dE[k * FEA + c];
  #pragma unroll
  for (int k = DRUG_NUM; k < NUM_NODE; ++k) a += rs[k] * cE[(k - DRUG_NUM) * FEA + c];
  edge_group[s * FEA + c] = a / fmaxf(cnt[s], 1.f);
}

// ---------------- K3b: fc / projections / head-softmax / node_rep ----------------
__global__ __launch_bounds__(128) void node_rep_k(
    const float* __restrict__ edge_group, const float* __restrict__ dE,
    const float* __restrict__ cE, const float* __restrict__ node_proj,
    const float* __restrict__ edge_proj, const float* __restrict__ fc_w,
    const float* __restrict__ fc_b, float* __restrict__ node_rep)
{
  __shared__ float fw[FEA][FEA + 1];
  __shared__ float eg[2][FEA];
  __shared__ float mg[FEA];
  __shared__ float nm[FEA];
  __shared__ float em[2][FEA];
  __shared__ float ef[2][FEA];
  __shared__ float sc[4][2];
  __shared__ float wgt[4][2];

  const int n = blockIdx.x, c = threadIdx.x;
  const int isdrug = (n < DRUG_NUM);
  eg[0][c] = edge_group[(n * 2 + 0) * FEA + c];
  eg[1][c] = edge_group[(n * 2 + 1) * FEA + c];
  mg[c] = isdrug ? dE[n * FEA + c] : cE[(n - DRUG_NUM) * FEA + c];
  for (int r = 0; r < FEA; ++r) fw[r][c] = fc_w[r * FEA + c];
  __syncthreads();

  for (int e = 0; e < 2; ++e) {
    float a = fc_b[c];
    #pragma unroll 8
    for (int k = 0; k < FEA; ++k) a += eg[e][k] * fw[c][k];
    ef[e][c] = fmaxf(a, 0.f);
  }
  {
    const float* P = node_proj + (size_t)(isdrug ? 0 : 1) * FEA * FEA;
    float a = 0.f;
    #pragma unroll 8
    for (int k = 0; k < FEA; ++k) a += mg[k] * P[k * FEA + c];
    nm[c] = a;
  }
  for (int e = 0; e < 2; ++e) {
    const float* P = edge_proj + (size_t)((isdrug ? 0 : 2) + e) * FEA * FEA;
    float a = 0.f;
    #pragma unroll 8
    for (int k = 0; k < FEA; ++k) a += eg[e][k] * P[k * FEA + c];
    em[e][c] = a;
  }
  __syncthreads();

  if (c < 8) {
    const int h = c >> 1, e = c & 1;
    float s = 0.f;
    #pragma unroll
    for (int d = 0; d < 32; ++d) s += nm[h * 32 + d] * em[e][h * 32 + d];
    sc[h][e] = s * 0.17677669529663687f;
  }
  __syncthreads();
  if (c < 2) {
    const int e = c;
    const float mx = fmaxf(fmaxf(sc[0][e], sc[1][e]), fmaxf(sc[2][e], sc[3][e]));
    const float t0 = expf(sc[0][e] - mx), t1 = expf(sc[1][e] - mx);
    const float t2 = expf(sc[2][e] - mx), t3 = expf(sc[3][e] - mx);
    const float inv = 1.f / (t0 + t1 + t2 + t3);
    wgt[0][e] = t0 * inv; wgt[1][e] = t1 * inv;
    wgt[2][e] = t2 * inv; wgt[3][e] = t3 * inv;
  }
  __syncthreads();

  const int h = c >> 5;
  const float v = fmaxf(wgt[h][0] * ef[0][c], 0.f) + fmaxf(wgt[h][1] * ef[1][c], 0.f);
  node_rep[n * FEA + c] = v;
}

// ---------------- cvt: fp32 -> bf16 hi/lo split (RTNE) ----------------
__global__ __launch_bounds__(256) void cvt_split_k(
    const float* __restrict__ src, unsigned short* __restrict__ hi,
    unsigned short* __restrict__ lo, int n)
{
  const int i = blockIdx.x * 256 + threadIdx.x;
  if (i < n) {
    const float v = src[i];
    const unsigned short h = f2bf_rtne(v);
    hi[i] = h;
    lo[i] = f2bf_rtne(v - bf2f(h));
  }
}

// ---------------- K4a: BN'd node_rep per decoder part -> nodeBN[3][70][128] ----
__global__ __launch_bounds__(128) void nodebn_k(
    const float* __restrict__ node_rep,
    const float* __restrict__ gam, const float* __restrict__ bet,
    const float* __restrict__ mean, const float* __restrict__ var,
    unsigned short* __restrict__ nb_hi, unsigned short* __restrict__ nb_lo)
{
  const int n = blockIdx.x, p = blockIdx.y, c = threadIdx.x;
  const int j = p * FEA + c;
  float v = node_rep[n * FEA + c];
  v = (v - mean[j]) * rsqrtf(var[j] + 1e-5f) * gam[j] + bet[j];
  const int o = (p * NUM_NODE + n) * FEA + c;
  const unsigned short h = f2bf_rtne(v);
  nb_hi[o] = h;
  nb_lo[o] = f2bf_rtne(v - bf2f(h));
}

// ---------------- K4b: h1 = lrelu(emb @ w1^T + b1), split-bf16 MFMA ----
// Software-pipelined: loads of k-step kk+1 issued before MFMAs of kk.
// __launch_bounds__(256,2): grid is 2 blocks/CU anyway; lift the VGPR cap so
// all 12 operand frags of the next step stay in flight.
#define L1_LOAD(kk, b) do {                                                   \
    const int p_ = (kk) >> 2, q_ = (kk) & 3;                                  \
    const int k0_ = (kk) * 32;                                                \
    _Pragma("unroll")                                                         \
    for (int t = 0; t < 4; ++t) {                                             \
      const int abase = (p_ * NUM_NODE + idx[t][p_]) * FEA + q_ * 32 + g * 8; \
      ah[b][t] = *(const bfrag*)(nb_hi + abase);                              \
      al[b][t] = *(const bfrag*)(nb_lo + abase);                              \
    }                                                                         \
    bh[b][0] = *(const bfrag*)(w_hi + wrow0 + k0_);                           \
    bh[b][1] = *(const bfrag*)(w_hi + wrow1 + k0_);                           \
    bl[b][0] = *(const bfrag*)(w_lo + wrow0 + k0_);                           \
    bl[b][1] = *(const bfrag*)(w_lo + wrow1 + k0_);                           \
  } while (0)

__global__ __launch_bounds__(256, 2) void lin1_k(
    const unsigned short* __restrict__ nb_hi, const unsigned short* __restrict__ nb_lo,
    const int* __restrict__ index,
    const unsigned short* __restrict__ w_hi, const unsigned short* __restrict__ w_lo,
    const float* __restrict__ bias,
    unsigned short* __restrict__ h_hi, unsigned short* __restrict__ h_lo)
{
  const int lane = threadIdx.x & 63, wave = threadIdx.x >> 6;
  const int r16 = lane & 15, g = lane >> 4;
  const int wr = wave >> 1, wc = wave & 1;
  const int rowbase = blockIdx.y * 128 + wr * 64;
  const int colbase = blockIdx.x * 64 + wc * 32;

  int idx[4][3];
  #pragma unroll
  for (int t = 0; t < 4; ++t) {
    const int r = rowbase + t * 16 + r16;
    idx[t][0] = index[r * 3 + 0];
    idx[t][1] = index[r * 3 + 1];
    idx[t][2] = index[r * 3 + 2];
  }

  f32x4 acc[4][2];
  #pragma unroll
  for (int t = 0; t < 4; ++t) {
    acc[t][0] = (f32x4){0.f, 0.f, 0.f, 0.f};
    acc[t][1] = (f32x4){0.f, 0.f, 0.f, 0.f};
  }

  const size_t wrow0 = (size_t)(colbase + r16) * 384 + g * 8;
  const size_t wrow1 = (size_t)(colbase + 16 + r16) * 384 + g * 8;

  bfrag ah[2][4], al[2][4], bh[2][2], bl[2][2];
  L1_LOAD(0, 0);
  #pragma unroll
  for (int kk = 0; kk < 12; ++kk) {        // all indices compile-time post-unroll
    const int cur = kk & 1, nxt = cur ^ 1;
    if (kk < 11) L1_LOAD(kk + 1, nxt);
    #pragma unroll
    for (int t = 0; t < 4; ++t) {
      acc[t][0] = MFMA16(ah[cur][t], bh[cur][0], acc[t][0]);
      acc[t][0] = MFMA16(ah[cur][t], bl[cur][0], acc[t][0]);
      acc[t][0] = MFMA16(al[cur][t], bh[cur][0], acc[t][0]);
      acc[t][1] = MFMA16(ah[cur][t], bh[cur][1], acc[t][1]);
      acc[t][1] = MFMA16(ah[cur][t], bl[cur][1], acc[t][1]);
      acc[t][1] = MFMA16(al[cur][t], bh[cur][1], acc[t][1]);
    }
  }

  #pragma unroll
  for (int t = 0; t < 4; ++t) {
    #pragma unroll
    for (int u = 0; u < 2; ++u) {
      const int col = colbase + u * 16 + r16;
      const float bv = bias[col];
      #pragma unroll
      for (int i = 0; i < 4; ++i) {
        float v = acc[t][u][i] + bv;
        v = v > 0.f ? v : 0.5f * v;
        const size_t o = (size_t)(rowbase + t * 16 + g * 4 + i) * 512 + col;
        const unsigned short h = f2bf_rtne(v);
        h_hi[o] = h;
        h_lo[o] = f2bf_rtne(v - bf2f(h));
      }
    }
  }
}

// ---------------- K4c: hout = lrelu(h1 @ w2^T + b2), fp32 out ----------------
#define L2_LOAD(kk, b) do {                                      \
    const int k0_ = (kk) * 32;                                   \
    ah[b][0] = *(const bfrag*)(a_hi + arow0 + k0_);              \
    ah[b][1] = *(const bfrag*)(a_hi + arow1 + k0_);              \
    al[b][0] = *(const bfrag*)(a_lo + arow0 + k0_);              \
    al[b][1] = *(const bfrag*)(a_lo + arow1 + k0_);              \
    bh[b][0] = *(const bfrag*)(w_hi + wrow0 + k0_);              \
    bh[b][1] = *(const bfrag*)(w_hi + wrow1 + k0_);              \
    bl[b][0] = *(const bfrag*)(w_lo + wrow0 + k0_);              \
    bl[b][1] = *(const bfrag*)(w_lo + wrow1 + k0_);              \
  } while (0)

__global__ __launch_bounds__(512, 2) void lin2_k(
    const unsigned short* __restrict__ a_hi, const unsigned short* __restrict__ a_lo,
    const unsigned short* __restrict__ w_hi, const unsigned short* __restrict__ w_lo,
    const float* __restrict__ bias, float* __restrict__ C)
{
  const int lane = threadIdx.x & 63, wave = threadIdx.x >> 6;
  const int r16 = lane & 15, g = lane >> 4;
  const int wr = wave >> 1, wc = wave & 1;
  const int rowbase = blockIdx.y * 128 + wr * 32;
  const int colbase = blockIdx.x * 64 + wc * 32;

  const size_t arow0 = (size_t)(rowbase + r16) * 512 + g * 8;
  const size_t arow1 = (size_t)(rowbase + 16 + r16) * 512 + g * 8;
  const size_t wrow0 = (size_t)(colbase + r16) * 512 + g * 8;
  const size_t wrow1 = (size_t)(colbase + 16 + r16) * 512 + g * 8;

  f32x4 acc00 = {0.f, 0.f, 0.f, 0.f}, acc01 = acc00, acc10 = acc00, acc11 = acc00;

  bfrag ah[2][2], al[2][2], bh[2][2], bl[2][2];
  L2_LOAD(0, 0);
  #pragma unroll
  for (int kk = 0; kk < 16; ++kk) {
    const int cur = kk & 1, nxt = cur ^ 1;
    if (kk < 15) L2_LOAD(kk + 1, nxt);
    acc00 = MFMA16(ah[cur][0], bh[cur][0], acc00);
    acc00 = MFMA16(ah[cur][0], bl[cur][0], acc00);
    acc00 = MFMA16(al[cur][0], bh[cur][0], acc00);
    acc01 = MFMA16(ah[cur][0], bh[cur][1], acc01);
    acc01 = MFMA16(ah[cur][0], bl[cur][1], acc01);
    acc01 = MFMA16(al[cur][0], bh[cur][1], acc01);
    acc10 = MFMA16(ah[cur][1], bh[cur][0], acc10);
    acc10 = MFMA16(ah[cur][1], bl[cur][0], acc10);
    acc10 = MFMA16(al[cur][1], bh[cur][0], acc10);
    acc11 = MFMA16(ah[cur][1], bh[cur][1], acc11);
    acc11 = MFMA16(ah[cur][1], bl[cur][1], acc11);
    acc11 = MFMA16(al[cur][1], bh[cur][1], acc11);
  }

  f32x4 av[2][2] = {{acc00, acc01}, {acc10, acc11}};
  #pragma unroll
  for (int t = 0; t < 2; ++t) {
    #pragma unroll
    for (int u = 0; u < 2; ++u) {
      const int col = colbase + u * 16 + r16;
      const float bv = bias[col];
      #pragma unroll
      for (int i = 0; i < 4; ++i) {
        float v = av[t][u][i] + bv;
        v = v > 0.f ? v : 0.5f * v;
        C[(size_t)(rowbase + t * 16 + g * 4 + i) * 256 + col] = v;
      }
    }
  }
}

// ---------------- K4d: out0 = sigmoid(h @ w3 + b3) ----------------
__global__ __launch_bounds__(256) void lin3_k(
    const float* __restrict__ H, const float* __restrict__ w3,
    const float* __restrict__ b3, float* __restrict__ out)
{
  const int row = blockIdx.x * 4 + (threadIdx.x >> 6);
  const int lane = threadIdx.x & 63;
  const float4 h = *(const float4*)(H + (size_t)row * 256 + lane * 4);
  const float4 w = *(const float4*)(w3 + lane * 4);
  float v = h.x * w.x + h.y * w.y + h.z * w.z + h.w * w.w;
  #pragma unroll
  for (int off = 32; off; off >>= 1) v += __shfl_down(v, off);
  if (lane == 0) out[row] = 1.f / (1.f + expf(-(v + b3[0])));
}

extern "C" void kernel_launch(void* const* d_in, const int* in_sizes, int n_in,
                              void* d_out, int out_size, void* d_ws, size_t ws_size,
                              hipStream_t stream) {
  const float* dth_cls  = (const float*)d_in[2];
  const float* dth_dc   = (const float*)d_in[3];
  const int*   he_node  = (const int*)d_in[4];
  const int*   he_edge  = (const int*)d_in[5];
  const int*   index    = (const int*)d_in[7];
  const float* dE       = (const float*)d_in[8];
  const float* cE       = (const float*)d_in[9];
  const float* node_proj= (const float*)d_in[10];
  const float* edge_proj= (const float*)d_in[11];
  const float* fc_w     = (const float*)d_in[12];
  const float* fc_b     = (const float*)d_in[13];
  const float* bn_g     = (const float*)d_in[14];
  const float* bn_b     = (const float*)d_in[15];
  const float* bn_m     = (const float*)d_in[16];
  const float* bn_v     = (const float*)d_in[17];
  const float* w1       = (const float*)d_in[18];
  const float* b1       = (const float*)d_in[19];
  const float* w2       = (const float*)d_in[20];
  const float* b2       = (const float*)d_in[21];
  const float* w3       = (const float*)d_in[22];
  const float* b3       = (const float*)d_in[23];

  float* out0 = (float*)d_out;
  float* hout = out0 + BATCH;                      // [8192,256] fp32, 2nd output

  float* ws = (float*)d_ws;
  float*          cnt_f     = ws + 9856;                       // -> 9996
  float*          edge_group= ws + 10048;                      // -> 27968
  float*          node_rep  = ws + 28032;                      // -> 36992
  unsigned short* nb_hi     = (unsigned short*)(ws + 37056);   // 26880 bf16
  unsigned short* nb_lo     = (unsigned short*)(ws + 50560);   // 26880 bf16
  unsigned short* w1_hi     = (unsigned short*)(ws + 64000);   // 196608 bf16
  unsigned short* w1_lo     = (unsigned short*)(ws + 162304);
  unsigned short* w2_hi     = (unsigned short*)(ws + 260608);  // 131072 bf16
  unsigned short* w2_lo     = (unsigned short*)(ws + 326144);
  unsigned short* h1_hi     = (unsigned short*)(ws + 391744);  // 8192*512 bf16 -> +2097152 fl
  unsigned short* h1_lo     = (unsigned short*)(ws + 2488960); // -> end 4586112 fl (18.3 MB)
  // seg scratch aliased into h1 span (fully consumed before lin1 writes h1):
  int*            sorted_off= (int*)(ws + 391744);             // 524288 -> 916032
  int*            hist_t    = (int*)(ws + 916032);             // 71680
  int*            scan_t    = (int*)(ws + 987712);             // 71680
  int*            seg_total = (int*)(ws + 1059392);            // 140
  int*            seg_base  = (int*)(ws + 1059532);            // 141
  float*          partial   = ws + 1059680;                    // 140*64*70=627200 -> 1686880

  // weight split conversions (independent of everything else)
  cvt_split_k<<<(512 * 384 + 255) / 256, 256, 0, stream>>>(w1, w1_hi, w1_lo, 512 * 384);
  cvt_split_k<<<(256 * 512 + 255) / 256, 256, 0, stream>>>(w2, w2_hi, w2_lo, 256 * 512);

  // segment-mean pipeline
  hist_k<<<NB_H, 256, 0, stream>>>(he_node, he_edge, hist_t);
  scan_blocks_k<<<NSEG, NB_H, 0, stream>>>(hist_t, scan_t, seg_total);
  base_k<<<1, 256, 0, stream>>>(seg_total, seg_base, cnt_f);
  scatter_k<<<NB_H, 256, 0, stream>>>(he_node, he_edge, scan_t, seg_base, sorted_off);
  seg_acc_k<<<dim3(NSEG, NCHUNK / 4), 256, 0, stream>>>(dth_cls, dth_dc, sorted_off,
                                                        seg_base, partial);
  seg_fin_edge_k<<<NSEG, 128, 0, stream>>>(partial, cnt_f, dE, cE, edge_group);
  node_rep_k<<<NUM_NODE, 128, 0, stream>>>(edge_group, dE, cE, node_proj, edge_proj,
                                           fc_w, fc_b, node_rep);

  // decoder: split-bf16 MFMA, emb gathered on the fly
  nodebn_k<<<dim3(NUM_NODE, 3), 128, 0, stream>>>(node_rep, bn_g, bn_b, bn_m, bn_v,
                                                  nb_hi, nb_lo);
  lin1_k<<<dim3(512 / 64, BATCH / 128), 256, 0, stream>>>(nb_hi, nb_lo, index,
                                                          w1_hi, w1_lo, b1, h1_hi, h1_lo);
  lin2_k<<<dim3(256 / 64, BATCH / 128), 512, 0, stream>>>(h1_hi, h1_lo, w2_hi, w2_lo,
                                                          b2, hout);
  lin3_k<<<BATCH / 4, 256, 0, stream>>>(hout, w3, b3, out0);
}

// Round 10
// 137.422 us; speedup vs baseline: 1.1455x; 1.1455x over previous
//
#include <hip/hip_runtime.h>

#define NUM_CLS   131072
#define NUM_NODE  70
#define DRUG_NUM  38
#define NSEG      140
#define ROWLEN    70
#define FEA       128
#define MTOT      524288
#define BATCH     8192
#define NB_H      512                 // histogram / scatter blocks (1024 entries each)
#define NCHUNK    64                  // accumulate chunks per segment

typedef __attribute__((ext_vector_type(8))) short bfrag;
typedef __attribute__((ext_vector_type(4))) float f32x4;
typedef __attribute__((ext_vector_type(4))) unsigned short us4;

__device__ __forceinline__ unsigned short f2bf_rtne(float x) {
  unsigned int u = __float_as_uint(x);
  u = (u + 0x7fffu + ((u >> 16) & 1u)) >> 16;
  return (unsigned short)u;
}
__device__ __forceinline__ float bf2f(unsigned short h) {
  return __uint_as_float((unsigned int)h << 16);
}
#define MFMA16(a, b, c) __builtin_amdgcn_mfma_f32_16x16x32_bf16((a), (b), (c), 0, 0, 0)

// ---------------- P1: per-block segment histogram ----------------
__global__ __launch_bounds__(256) void hist_k(
    const int* __restrict__ he_node, const int* __restrict__ he_edge,
    int* __restrict__ hist_t)        // [NSEG][NB_H]
{
  __shared__ int h[NSEG];
  const int tid = threadIdx.x;
  if (tid < NSEG) h[tid] = 0;
  __syncthreads();
  const int base = blockIdx.x * 1024;
  #pragma unroll
  for (int t = 0; t < 4; ++t) {
    const int e = base + t * 256 + tid;
    const int seg = he_node[e] * 2 + (he_edge[e] >= NUM_CLS);
    atomicAdd(&h[seg], 1);
  }
  __syncthreads();
  if (tid < NSEG) hist_t[tid * NB_H + blockIdx.x] = h[tid];
}

// ---------------- P2a: per-seg exclusive scan over blocks ----------------
__global__ __launch_bounds__(512) void scan_blocks_k(
    const int* __restrict__ hist_t, int* __restrict__ scan_t,
    int* __restrict__ seg_total)
{
  __shared__ int v[NB_H];
  const int s = blockIdx.x, tid = threadIdx.x;
  const int x0 = hist_t[s * NB_H + tid];
  v[tid] = x0;
  __syncthreads();
  for (int off = 1; off < NB_H; off <<= 1) {
    int y = (tid >= off) ? v[tid - off] : 0;
    __syncthreads();
    v[tid] += y;
    __syncthreads();
  }
  scan_t[s * NB_H + tid] = v[tid] - x0;     // exclusive
  if (tid == NB_H - 1) seg_total[s] = v[tid];
}

// ---------------- P2b: segment bases ----------------
__global__ __launch_bounds__(256) void base_k(
    const int* __restrict__ seg_total, int* __restrict__ seg_base,
    float* __restrict__ cnt_f)
{
  __shared__ int tot[NSEG];
  __shared__ int bs[NSEG + 1];
  const int tid = threadIdx.x;
  if (tid < NSEG) tot[tid] = seg_total[tid];
  __syncthreads();
  if (tid == 0) {
    int run = 0;
    for (int s = 0; s < NSEG; ++s) { bs[s] = run; run += tot[s]; }
    bs[NSEG] = run;
  }
  __syncthreads();
  if (tid < NSEG) { seg_base[tid] = bs[tid]; cnt_f[tid] = (float)tot[tid]; }
  if (tid == NSEG) seg_base[NSEG] = bs[NSEG];
}

// ---------------- P3: scatter row-offsets into seg-sorted order ----------------
__global__ __launch_bounds__(256) void scatter_k(
    const int* __restrict__ he_node, const int* __restrict__ he_edge,
    const int* __restrict__ scan_t, const int* __restrict__ seg_base,
    int* __restrict__ sorted_off)
{
  __shared__ int rank[NSEG];
  __shared__ int base[NSEG];
  const int tid = threadIdx.x;
  if (tid < NSEG) {
    rank[tid] = 0;
    base[tid] = seg_base[tid] + scan_t[tid * NB_H + blockIdx.x];
  }
  __syncthreads();
  const int e0 = blockIdx.x * 1024;
  #pragma unroll
  for (int t = 0; t < 4; ++t) {
    const int e = e0 + t * 256 + tid;
    const int node = he_node[e];
    const int edge = he_edge[e];
    const int isdc = (edge >= NUM_CLS);
    const int seg  = node * 2 + isdc;
    const int off  = (isdc ? edge - NUM_CLS : edge) * ROWLEN;
    const int r = atomicAdd(&rank[seg], 1);
    sorted_off[base[seg] + r] = off;
  }
}

// ---------------- P4: wave-per-entry accumulate; lane l owns cols l, 64+l ----
// 16 entries unrolled -> 32 row loads + 16 offset loads in flight per wave.
__global__ __launch_bounds__(256) void seg_acc_k(
    const float* __restrict__ dth_cls, const float* __restrict__ dth_dc,
    const int* __restrict__ sorted_off, const int* __restrict__ seg_base,
    float* __restrict__ partial)     // [NSEG][NCHUNK][ROWLEN]
{
  const int s = blockIdx.x;
  const int wid = threadIdx.x >> 6, lane = threadIdx.x & 63;
  const int chunk = blockIdx.y * 4 + wid;       // gridDim.y = NCHUNK/4
  const int b0 = seg_base[s];
  const int n  = seg_base[s + 1] - b0;
  const int c0 = b0 + (int)(((long long)n * chunk) >> 6);
  const int c1 = b0 + (int)(((long long)n * (chunk + 1)) >> 6);
  const float* __restrict__ T = (s & 1) ? dth_dc : dth_cls;
  const bool tail = (lane < ROWLEN - 64);

  float accm = 0.f, acct = 0.f;
  int i = c0;
  for (; i + 16 <= c1; i += 16) {
    int o[16];
    #pragma unroll
    for (int u = 0; u < 16; ++u) o[u] = sorted_off[i + u];  // wave-uniform
    float v[16];
    #pragma unroll
    for (int u = 0; u < 16; ++u) v[u] = T[o[u] + lane];
    float t[16];
    #pragma unroll
    for (int u = 0; u < 16; ++u) t[u] = tail ? T[o[u] + 64 + lane] : 0.f;
    #pragma unroll
    for (int u = 0; u < 16; ++u) { accm += v[u]; acct += t[u]; }
  }
  for (; i < c1; ++i) {
    const int o = sorted_off[i];
    accm += T[o + lane];
    if (tail) acct += T[o + 64 + lane];
  }

  float* dst = partial + ((size_t)s * NCHUNK + chunk) * ROWLEN;
  dst[lane] = accm;
  if (tail) dst[64 + lane] = acct;
}

// ---------------- P5+K3a fused: rowsum reduce + edge_group GEMV ----------------
__global__ __launch_bounds__(128) void seg_fin_edge_k(
    const float* __restrict__ partial, const float* __restrict__ cnt,
    const float* __restrict__ dE, const float* __restrict__ cE,
    float* __restrict__ edge_group)
{
  __shared__ float rs[ROWLEN];
  const int s = blockIdx.x, c = threadIdx.x;
  if (c < ROWLEN) {
    float v = 0.f;
    const float* p = partial + (size_t)s * NCHUNK * ROWLEN + c;
    #pragma unroll 8
    for (int k = 0; k < NCHUNK; ++k) v += p[k * ROWLEN];
    rs[c] = v;
  }
  __syncthreads();
  float a = 0.f;
  #pragma unroll
  for (int k = 0; k < DRUG_NUM; ++k) a += rs[k] * dE[k * FEA + c];
  #pragma unroll
  for (int k = DRUG_NUM; k < NUM_NODE; ++k) a += rs[k] * cE[(k - DRUG_NUM) * FEA + c];
  edge_group[s * FEA + c] = a / fmaxf(cnt[s], 1.f);
}

// ---------------- K3b: fc / projections / head-softmax / node_rep ----------------
__global__ __launch_bounds__(128) void node_rep_k(
    const float* __restrict__ edge_group, const float* __restrict__ dE,
    const float* __restrict__ cE, const float* __restrict__ node_proj,
    const float* __restrict__ edge_proj, const float* __restrict__ fc_w,
    const float* __restrict__ fc_b, float* __restrict__ node_rep)
{
  __shared__ float fw[FEA][FEA + 1];
  __shared__ float eg[2][FEA];
  __shared__ float mg[FEA];
  __shared__ float nm[FEA];
  __shared__ float em[2][FEA];
  __shared__ float ef[2][FEA];
  __shared__ float sc[4][2];
  __shared__ float wgt[4][2];

  const int n = blockIdx.x, c = threadIdx.x;
  const int isdrug = (n < DRUG_NUM);
  eg[0][c] = edge_group[(n * 2 + 0) * FEA + c];
  eg[1][c] = edge_group[(n * 2 + 1) * FEA + c];
  mg[c] = isdrug ? dE[n * FEA + c] : cE[(n - DRUG_NUM) * FEA + c];
  for (int r = 0; r < FEA; ++r) fw[r][c] = fc_w[r * FEA + c];
  __syncthreads();

  for (int e = 0; e < 2; ++e) {
    float a = fc_b[c];
    #pragma unroll 8
    for (int k = 0; k < FEA; ++k) a += eg[e][k] * fw[c][k];
    ef[e][c] = fmaxf(a, 0.f);
  }
  {
    const float* P = node_proj + (size_t)(isdrug ? 0 : 1) * FEA * FEA;
    float a = 0.f;
    #pragma unroll 8
    for (int k = 0; k < FEA; ++k) a += mg[k] * P[k * FEA + c];
    nm[c] = a;
  }
  for (int e = 0; e < 2; ++e) {
    const float* P = edge_proj + (size_t)((isdrug ? 0 : 2) + e) * FEA * FEA;
    float a = 0.f;
    #pragma unroll 8
    for (int k = 0; k < FEA; ++k) a += eg[e][k] * P[k * FEA + c];
    em[e][c] = a;
  }
  __syncthreads();

  if (c < 8) {
    const int h = c >> 1, e = c & 1;
    float s = 0.f;
    #pragma unroll
    for (int d = 0; d < 32; ++d) s += nm[h * 32 + d] * em[e][h * 32 + d];
    sc[h][e] = s * 0.17677669529663687f;
  }
  __syncthreads();
  if (c < 2) {
    const int e = c;
    const float mx = fmaxf(fmaxf(sc[0][e], sc[1][e]), fmaxf(sc[2][e], sc[3][e]));
    const float t0 = expf(sc[0][e] - mx), t1 = expf(sc[1][e] - mx);
    const float t2 = expf(sc[2][e] - mx), t3 = expf(sc[3][e] - mx);
    const float inv = 1.f / (t0 + t1 + t2 + t3);
    wgt[0][e] = t0 * inv; wgt[1][e] = t1 * inv;
    wgt[2][e] = t2 * inv; wgt[3][e] = t3 * inv;
  }
  __syncthreads();

  const int h = c >> 5;
  const float v = fmaxf(wgt[h][0] * ef[0][c], 0.f) + fmaxf(wgt[h][1] * ef[1][c], 0.f);
  node_rep[n * FEA + c] = v;
}

// ---------------- cvt: fp32 -> bf16 hi/lo split (RTNE) ----------------
__global__ __launch_bounds__(256) void cvt_split_k(
    const float* __restrict__ src, unsigned short* __restrict__ hi,
    unsigned short* __restrict__ lo, int n)
{
  const int i = blockIdx.x * 256 + threadIdx.x;
  if (i < n) {
    const float v = src[i];
    const unsigned short h = f2bf_rtne(v);
    hi[i] = h;
    lo[i] = f2bf_rtne(v - bf2f(h));
  }
}

// ---------------- K4a: Hnode[p][n][c] = BN(node_rep[n])[p-block] . w1[c] ----
// Exact fp32 layer-1 for the 210 distinct (part,node) rows.
__global__ __launch_bounds__(512) void node_gemm_k(
    const float* __restrict__ node_rep,
    const float* __restrict__ gam, const float* __restrict__ bet,
    const float* __restrict__ mean, const float* __restrict__ var,
    const float* __restrict__ w1, float* __restrict__ Hnode)
{
  __shared__ float a[FEA];
  const int n = blockIdx.x, p = blockIdx.y, c = threadIdx.x;
  if (c < FEA) {
    const int j = p * FEA + c;
    const float v = node_rep[n * FEA + c];
    a[c] = (v - mean[j]) * rsqrtf(var[j] + 1e-5f) * gam[j] + bet[j];
  }
  __syncthreads();
  const float* wrow = w1 + (size_t)c * 384 + p * FEA;
  float s = 0.f;
  #pragma unroll
  for (int k = 0; k < FEA; k += 4) {
    const float4 wv = *(const float4*)(wrow + k);
    s += a[k] * wv.x + a[k + 1] * wv.y + a[k + 2] * wv.z + a[k + 3] * wv.w;
  }
  Hnode[((size_t)p * NUM_NODE + n) * 512 + c] = s;
}

// ---------------- K4b: h1[r] = lrelu(Hnode[0][i0]+Hnode[1][i1]+Hnode[2][i2]+b1) ----
// Coalesced float4 gather from the 430KB L2-resident Hnode table.
__global__ __launch_bounds__(512) void gather_add_k(
    const float* __restrict__ Hnode, const int* __restrict__ index,
    const float* __restrict__ b1,
    unsigned short* __restrict__ h_hi, unsigned short* __restrict__ h_lo)
{
  const int r = blockIdx.x * 4 + (threadIdx.x >> 7);
  const int j = (threadIdx.x & 127) * 4;
  const int i0 = index[r * 3 + 0], i1 = index[r * 3 + 1], i2 = index[r * 3 + 2];
  const float4 v0 = *(const float4*)(Hnode + ((size_t)0 * NUM_NODE + i0) * 512 + j);
  const float4 v1 = *(const float4*)(Hnode + ((size_t)1 * NUM_NODE + i1) * 512 + j);
  const float4 v2 = *(const float4*)(Hnode + ((size_t)2 * NUM_NODE + i2) * 512 + j);
  const float4 bb = *(const float4*)(b1 + j);
  float h[4];
  h[0] = v0.x + v1.x + v2.x + bb.x;
  h[1] = v0.y + v1.y + v2.y + bb.y;
  h[2] = v0.z + v1.z + v2.z + bb.z;
  h[3] = v0.w + v1.w + v2.w + bb.w;
  us4 hi, lo;
  #pragma unroll
  for (int u = 0; u < 4; ++u) {
    const float v = h[u] > 0.f ? h[u] : 0.5f * h[u];
    const unsigned short hh = f2bf_rtne(v);
    hi[u] = hh;
    lo[u] = f2bf_rtne(v - bf2f(hh));
  }
  *(us4*)(h_hi + (size_t)r * 512 + j) = hi;
  *(us4*)(h_lo + (size_t)r * 512 + j) = lo;
}

// ---------------- K4c: hout = lrelu(h1 @ w2^T + b2), fp32 out ----------------
#define L2_LOAD(kk, b) do {                                      \
    const int k0_ = (kk) * 32;                                   \
    ah[b][0] = *(const bfrag*)(a_hi + arow0 + k0_);              \
    ah[b][1] = *(const bfrag*)(a_hi + arow1 + k0_);              \
    al[b][0] = *(const bfrag*)(a_lo + arow0 + k0_);              \
    al[b][1] = *(const bfrag*)(a_lo + arow1 + k0_);              \
    bh[b][0] = *(const bfrag*)(w_hi + wrow0 + k0_);              \
    bh[b][1] = *(const bfrag*)(w_hi + wrow1 + k0_);              \
    bl[b][0] = *(const bfrag*)(w_lo + wrow0 + k0_);              \
    bl[b][1] = *(const bfrag*)(w_lo + wrow1 + k0_);              \
  } while (0)

__global__ __launch_bounds__(512, 2) void lin2_k(
    const unsigned short* __restrict__ a_hi, const unsigned short* __restrict__ a_lo,
    const unsigned short* __restrict__ w_hi, const unsigned short* __restrict__ w_lo,
    const float* __restrict__ bias, float* __restrict__ C)
{
  const int lane = threadIdx.x & 63, wave = threadIdx.x >> 6;
  const int r16 = lane & 15, g = lane >> 4;
  const int wr = wave >> 1, wc = wave & 1;
  const int rowbase = blockIdx.y * 128 + wr * 32;
  const int colbase = blockIdx.x * 64 + wc * 32;

  const size_t arow0 = (size_t)(rowbase + r16) * 512 + g * 8;
  const size_t arow1 = (size_t)(rowbase + 16 + r16) * 512 + g * 8;
  const size_t wrow0 = (size_t)(colbase + r16) * 512 + g * 8;
  const size_t wrow1 = (size_t)(colbase + 16 + r16) * 512 + g * 8;

  f32x4 acc00 = {0.f, 0.f, 0.f, 0.f}, acc01 = acc00, acc10 = acc00, acc11 = acc00;

  bfrag ah[2][2], al[2][2], bh[2][2], bl[2][2];
  L2_LOAD(0, 0);
  #pragma unroll
  for (int kk = 0; kk < 16; ++kk) {
    const int cur = kk & 1, nxt = cur ^ 1;
    if (kk < 15) L2_LOAD(kk + 1, nxt);
    acc00 = MFMA16(ah[cur][0], bh[cur][0], acc00);
    acc00 = MFMA16(ah[cur][0], bl[cur][0], acc00);
    acc00 = MFMA16(al[cur][0], bh[cur][0], acc00);
    acc01 = MFMA16(ah[cur][0], bh[cur][1], acc01);
    acc01 = MFMA16(ah[cur][0], bl[cur][1], acc01);
    acc01 = MFMA16(al[cur][0], bh[cur][1], acc01);
    acc10 = MFMA16(ah[cur][1], bh[cur][0], acc10);
    acc10 = MFMA16(ah[cur][1], bl[cur][0], acc10);
    acc10 = MFMA16(al[cur][1], bh[cur][0], acc10);
    acc11 = MFMA16(ah[cur][1], bh[cur][1], acc11);
    acc11 = MFMA16(ah[cur][1], bl[cur][1], acc11);
    acc11 = MFMA16(al[cur][1], bh[cur][1], acc11);
  }

  f32x4 av[2][2] = {{acc00, acc01}, {acc10, acc11}};
  #pragma unroll
  for (int t = 0; t < 2; ++t) {
    #pragma unroll
    for (int u = 0; u < 2; ++u) {
      const int col = colbase + u * 16 + r16;
      const float bv = bias[col];
      #pragma unroll
      for (int i = 0; i < 4; ++i) {
        float v = av[t][u][i] + bv;
        v = v > 0.f ? v : 0.5f * v;
        C[(size_t)(rowbase + t * 16 + g * 4 + i) * 256 + col] = v;
      }
    }
  }
}

// ---------------- K4d: out0 = sigmoid(h @ w3 + b3) ----------------
__global__ __launch_bounds__(256) void lin3_k(
    const float* __restrict__ H, const float* __restrict__ w3,
    const float* __restrict__ b3, float* __restrict__ out)
{
  const int row = blockIdx.x * 4 + (threadIdx.x >> 6);
  const int lane = threadIdx.x & 63;
  const float4 h = *(const float4*)(H + (size_t)row * 256 + lane * 4);
  const float4 w = *(const float4*)(w3 + lane * 4);
  float v = h.x * w.x + h.y * w.y + h.z * w.z + h.w * w.w;
  #pragma unroll
  for (int off = 32; off; off >>= 1) v += __shfl_down(v, off);
  if (lane == 0) out[row] = 1.f / (1.f + expf(-(v + b3[0])));
}

extern "C" void kernel_launch(void* const* d_in, const int* in_sizes, int n_in,
                              void* d_out, int out_size, void* d_ws, size_t ws_size,
                              hipStream_t stream) {
  const float* dth_cls  = (const float*)d_in[2];
  const float* dth_dc   = (const float*)d_in[3];
  const int*   he_node  = (const int*)d_in[4];
  const int*   he_edge  = (const int*)d_in[5];
  const int*   index    = (const int*)d_in[7];
  const float* dE       = (const float*)d_in[8];
  const float* cE       = (const float*)d_in[9];
  const float* node_proj= (const float*)d_in[10];
  const float* edge_proj= (const float*)d_in[11];
  const float* fc_w     = (const float*)d_in[12];
  const float* fc_b     = (const float*)d_in[13];
  const float* bn_g     = (const float*)d_in[14];
  const float* bn_b     = (const float*)d_in[15];
  const float* bn_m     = (const float*)d_in[16];
  const float* bn_v     = (const float*)d_in[17];
  const float* w1       = (const float*)d_in[18];
  const float* b1       = (const float*)d_in[19];
  const float* w2       = (const float*)d_in[20];
  const float* b2       = (const float*)d_in[21];
  const float* w3       = (const float*)d_in[22];
  const float* b3       = (const float*)d_in[23];

  float* out0 = (float*)d_out;
  float* hout = out0 + BATCH;                      // [8192,256] fp32, 2nd output

  float* ws = (float*)d_ws;
  float*          cnt_f     = ws + 9856;                       // -> 9996
  float*          edge_group= ws + 10048;                      // -> 27968
  float*          node_rep  = ws + 28032;                      // -> 36992
  float*          Hnode     = ws + 37056;                      // 3*70*512 -> 144576
  unsigned short* w2_hi     = (unsigned short*)(ws + 144640);  // 131072 us -> 210176
  unsigned short* w2_lo     = (unsigned short*)(ws + 210176);  // -> 275712
  unsigned short* h1_hi     = (unsigned short*)(ws + 275712);  // 8192*512 us -> 2372864
  unsigned short* h1_lo     = (unsigned short*)(ws + 2372864); // -> 4470016 (17.9 MB)
  // seg scratch aliased into h1_hi span (all consumed before gather_add writes h1):
  int*            sorted_off= (int*)(ws + 275712);             // -> 800000
  int*            hist_t    = (int*)(ws + 800000);             // -> 871680
  int*            scan_t    = (int*)(ws + 871680);             // -> 943360
  int*            seg_total = (int*)(ws + 943360);             // -> 943500
  int*            seg_base  = (int*)(ws + 943500);             // -> 943641
  float*          partial   = ws + 943648;                     // 627200 -> 1570848

  // w2 split conversion (independent)
  cvt_split_k<<<(256 * 512 + 255) / 256, 256, 0, stream>>>(w2, w2_hi, w2_lo, 256 * 512);

  // segment-mean pipeline
  hist_k<<<NB_H, 256, 0, stream>>>(he_node, he_edge, hist_t);
  scan_blocks_k<<<NSEG, NB_H, 0, stream>>>(hist_t, scan_t, seg_total);
  base_k<<<1, 256, 0, stream>>>(seg_total, seg_base, cnt_f);
  scatter_k<<<NB_H, 256, 0, stream>>>(he_node, he_edge, scan_t, seg_base, sorted_off);
  seg_acc_k<<<dim3(NSEG, NCHUNK / 4), 256, 0, stream>>>(dth_cls, dth_dc, sorted_off,
                                                        seg_base, partial);
  seg_fin_edge_k<<<NSEG, 128, 0, stream>>>(partial, cnt_f, dE, cE, edge_group);
  node_rep_k<<<NUM_NODE, 128, 0, stream>>>(edge_group, dE, cE, node_proj, edge_proj,
                                           fc_w, fc_b, node_rep);

  // decoder layer 1: exact fp32 via 210-row table + coalesced gather-add
  node_gemm_k<<<dim3(NUM_NODE, 3), 512, 0, stream>>>(node_rep, bn_g, bn_b, bn_m, bn_v,
                                                     w1, Hnode);
  gather_add_k<<<BATCH / 4, 512, 0, stream>>>(Hnode, index, b1, h1_hi, h1_lo);

  // decoder layer 2 (split-bf16 MFMA) + head
  lin2_k<<<dim3(256 / 64, BATCH / 128), 512, 0, stream>>>(h1_hi, h1_lo, w2_hi, w2_lo,
                                                          b2, hout);
  lin3_k<<<BATCH / 4, 256, 0, stream>>>(hout, w3, b3, out0);
}

// Round 11
// 133.814 us; speedup vs baseline: 1.1764x; 1.0270x over previous
//
#include <hip/hip_runtime.h>

#define NUM_CLS   131072
#define NUM_NODE  70
#define DRUG_NUM  38
#define NSEG      140
#define ROWLEN    70
#define FEA       128
#define MTOT      524288
#define BATCH     8192
#define NBH2      128                 // histogram / scatter blocks (4096 entries each)
#define NSLICE    64                  // table slices (2048 rows = 573KB each)
#define NKEY      (NSEG * NSLICE)     // 8960 sort buckets

typedef __attribute__((ext_vector_type(8))) short bfrag;
typedef __attribute__((ext_vector_type(4))) float f32x4;
typedef __attribute__((ext_vector_type(4))) unsigned short us4;
typedef __attribute__((ext_vector_type(8))) unsigned short us8;

__device__ __forceinline__ unsigned short f2bf_rtne(float x) {
  unsigned int u = __float_as_uint(x);
  u = (u + 0x7fffu + ((u >> 16) & 1u)) >> 16;
  return (unsigned short)u;
}
__device__ __forceinline__ float bf2f(unsigned short h) {
  return __uint_as_float((unsigned int)h << 16);
}
#define MFMA16(a, b, c) __builtin_amdgcn_mfma_f32_16x16x32_bf16((a), (b), (c), 0, 0, 0)

// ---------------- P1: per-block histogram over (seg,slice) keys ----------------
__global__ __launch_bounds__(256) void hist_k(
    const int* __restrict__ he_node, const int* __restrict__ he_edge,
    int* __restrict__ hist_t)        // [NBH2][NKEY] block-major (coalesced writes)
{
  __shared__ int h[NKEY];
  const int tid = threadIdx.x;
  for (int i = tid; i < NKEY; i += 256) h[i] = 0;
  __syncthreads();
  const int base = blockIdx.x * 4096;
  #pragma unroll
  for (int t = 0; t < 16; ++t) {
    const int e = base + t * 256 + tid;
    const int node = he_node[e], edge = he_edge[e];
    const int isdc = (edge >= NUM_CLS);
    const int ridx = isdc ? edge - NUM_CLS : edge;
    const int key  = (node * 2 + isdc) * NSLICE + (ridx >> 11);
    atomicAdd(&h[key], 1);
  }
  __syncthreads();
  for (int i = tid; i < NKEY; i += 256)
    hist_t[(size_t)blockIdx.x * NKEY + i] = h[i];
}

// ---------------- P2a: per-key scan over the 128 hist blocks (coalesced) ----------------
__global__ __launch_bounds__(256) void col_scan_k(
    const int* __restrict__ hist_t, int* __restrict__ scan_t,
    int* __restrict__ tot)
{
  const int k = blockIdx.x * 256 + threadIdx.x;
  if (k >= NKEY) return;
  int run = 0;
  for (int b = 0; b < NBH2; ++b) {
    const int x = hist_t[(size_t)b * NKEY + k];
    scan_t[(size_t)b * NKEY + k] = run;
    run += x;
  }
  tot[k] = run;
}

// ---------------- P2b: exclusive scan of 8960 bucket totals ----------------
__global__ __launch_bounds__(1024) void base_k(
    const int* __restrict__ tot, int* __restrict__ base)
{
  __shared__ int ts[1024];
  const int tid = threadIdx.x;
  const int lo = tid * 9;
  const int hi = (lo + 9 < NKEY) ? lo + 9 : NKEY;
  int s = 0;
  for (int k = lo; k < hi; ++k) s += tot[k];
  ts[tid] = s;
  __syncthreads();
  for (int off = 1; off < 1024; off <<= 1) {
    int y = (tid >= off) ? ts[tid - off] : 0;
    __syncthreads();
    ts[tid] += y;
    __syncthreads();
  }
  int run = tid ? ts[tid - 1] : 0;
  for (int k = lo; k < hi; ++k) { base[k] = run; run += tot[k]; }
  if (tid == 1023) base[NKEY] = ts[1023];
}

// ---------------- P3: scatter row-offsets into (seg,slice)-sorted order ----------------
__global__ __launch_bounds__(256) void scatter_k(
    const int* __restrict__ he_node, const int* __restrict__ he_edge,
    const int* __restrict__ scan_t, const int* __restrict__ base,
    int* __restrict__ sorted_off)
{
  __shared__ int cursor[NKEY];
  const int tid = threadIdx.x;
  for (int i = tid; i < NKEY; i += 256)
    cursor[i] = base[i] + scan_t[(size_t)blockIdx.x * NKEY + i];
  __syncthreads();
  const int e0 = blockIdx.x * 4096;
  #pragma unroll
  for (int t = 0; t < 16; ++t) {
    const int e = e0 + t * 256 + tid;
    const int node = he_node[e], edge = he_edge[e];
    const int isdc = (edge >= NUM_CLS);
    const int ridx = isdc ? edge - NUM_CLS : edge;
    const int key  = (node * 2 + isdc) * NSLICE + (ridx >> 11);
    const int pos = atomicAdd(&cursor[key], 1);
    sorted_off[pos] = ridx * ROWLEN;
  }
}

// ---------------- P4: wave-per-bucket accumulate; XCD-localized slices ----------------
// Block bid -> work w=(bid%8)*280+bid/8 (bijective, 2240=8*280): XCD x gets
// g in {2x,2x+1} -> an 8-slice (4.6MB) L2-resident window per XCD.
__global__ __launch_bounds__(256) void seg_acc_k(
    const float* __restrict__ dth_cls, const float* __restrict__ dth_dc,
    const int* __restrict__ sorted_off, const int* __restrict__ bucket_base,
    float* __restrict__ partial)     // [NSEG][NSLICE][ROWLEN]
{
  const int bid = blockIdx.x;
  const int w = (bid & 7) * 280 + (bid >> 3);
  const int g = w / NSEG, s = w % NSEG;
  const int wid = threadIdx.x >> 6, lane = threadIdx.x & 63;
  const int t4 = g * 4 + wid;
  const int key = s * NSLICE + t4;
  const int c0 = bucket_base[key], c1 = bucket_base[key + 1];
  const float* __restrict__ T = (s & 1) ? dth_dc : dth_cls;
  const bool tail = (lane < ROWLEN - 64);

  float accm = 0.f, acct = 0.f;
  int i = c0;
  for (; i + 8 <= c1; i += 8) {
    int o[8];
    #pragma unroll
    for (int u = 0; u < 8; ++u) o[u] = sorted_off[i + u];
    float v[8];
    #pragma unroll
    for (int u = 0; u < 8; ++u) v[u] = T[o[u] + lane];
    float t[8];
    #pragma unroll
    for (int u = 0; u < 8; ++u) t[u] = tail ? T[o[u] + 64 + lane] : 0.f;
    #pragma unroll
    for (int u = 0; u < 8; ++u) { accm += v[u]; acct += t[u]; }
  }
  for (; i < c1; ++i) {
    const int o = sorted_off[i];
    accm += T[o + lane];
    if (tail) acct += T[o + 64 + lane];
  }

  float* dst = partial + (size_t)key * ROWLEN;
  dst[lane] = accm;
  if (tail) dst[64 + lane] = acct;
}

// ---------------- P5+K3a fused: rowsum reduce + edge_group GEMV ----------------
__global__ __launch_bounds__(128) void seg_fin_edge_k(
    const float* __restrict__ partial, const int* __restrict__ bucket_base,
    const float* __restrict__ dE, const float* __restrict__ cE,
    float* __restrict__ edge_group)
{
  __shared__ float rs[ROWLEN];
  const int s = blockIdx.x, c = threadIdx.x;
  if (c < ROWLEN) {
    float v = 0.f;
    const float* p = partial + (size_t)s * NSLICE * ROWLEN + c;
    #pragma unroll 8
    for (int k = 0; k < NSLICE; ++k) v += p[k * ROWLEN];
    rs[c] = v;
  }
  __syncthreads();
  const float cnt = (float)(bucket_base[s * NSLICE + NSLICE] - bucket_base[s * NSLICE]);
  float a = 0.f;
  #pragma unroll
  for (int k = 0; k < DRUG_NUM; ++k) a += rs[k] * dE[k * FEA + c];
  #pragma unroll
  for (int k = DRUG_NUM; k < NUM_NODE; ++k) a += rs[k] * cE[(k - DRUG_NUM) * FEA + c];
  edge_group[s * FEA + c] = a / fmaxf(cnt, 1.f);
}

// ---------------- K3b: fc / projections / head-softmax / node_rep ----------------
__global__ __launch_bounds__(128) void node_rep_k(
    const float* __restrict__ edge_group, const float* __restrict__ dE,
    const float* __restrict__ cE, const float* __restrict__ node_proj,
    const float* __restrict__ edge_proj, const float* __restrict__ fc_w,
    const float* __restrict__ fc_b, float* __restrict__ node_rep)
{
  __shared__ float fw[FEA][FEA + 1];
  __shared__ float eg[2][FEA];
  __shared__ float mg[FEA];
  __shared__ float nm[FEA];
  __shared__ float em[2][FEA];
  __shared__ float ef[2][FEA];
  __shared__ float sc[4][2];
  __shared__ float wgt[4][2];

  const int n = blockIdx.x, c = threadIdx.x;
  const int isdrug = (n < DRUG_NUM);
  eg[0][c] = edge_group[(n * 2 + 0) * FEA + c];
  eg[1][c] = edge_group[(n * 2 + 1) * FEA + c];
  mg[c] = isdrug ? dE[n * FEA + c] : cE[(n - DRUG_NUM) * FEA + c];
  for (int r = 0; r < FEA; ++r) fw[r][c] = fc_w[r * FEA + c];
  __syncthreads();

  for (int e = 0; e < 2; ++e) {
    float a = fc_b[c];
    #pragma unroll 8
    for (int k = 0; k < FEA; ++k) a += eg[e][k] * fw[c][k];
    ef[e][c] = fmaxf(a, 0.f);
  }
  {
    const float* P = node_proj + (size_t)(isdrug ? 0 : 1) * FEA * FEA;
    float a = 0.f;
    #pragma unroll 8
    for (int k = 0; k < FEA; ++k) a += mg[k] * P[k * FEA + c];
    nm[c] = a;
  }
  for (int e = 0; e < 2; ++e) {
    const float* P = edge_proj + (size_t)((isdrug ? 0 : 2) + e) * FEA * FEA;
    float a = 0.f;
    #pragma unroll 8
    for (int k = 0; k < FEA; ++k) a += eg[e][k] * P[k * FEA + c];
    em[e][c] = a;
  }
  __syncthreads();

  if (c < 8) {
    const int h = c >> 1, e = c & 1;
    float s = 0.f;
    #pragma unroll
    for (int d = 0; d < 32; ++d) s += nm[h * 32 + d] * em[e][h * 32 + d];
    sc[h][e] = s * 0.17677669529663687f;
  }
  __syncthreads();
  if (c < 2) {
    const int e = c;
    const float mx = fmaxf(fmaxf(sc[0][e], sc[1][e]), fmaxf(sc[2][e], sc[3][e]));
    const float t0 = expf(sc[0][e] - mx), t1 = expf(sc[1][e] - mx);
    const float t2 = expf(sc[2][e] - mx), t3 = expf(sc[3][e] - mx);
    const float inv = 1.f / (t0 + t1 + t2 + t3);
    wgt[0][e] = t0 * inv; wgt[1][e] = t1 * inv;
    wgt[2][e] = t2 * inv; wgt[3][e] = t3 * inv;
  }
  __syncthreads();

  const int h = c >> 5;
  const float v = fmaxf(wgt[h][0] * ef[0][c], 0.f) + fmaxf(wgt[h][1] * ef[1][c], 0.f);
  node_rep[n * FEA + c] = v;
}

// ---------------- K4a: Hnode[p][n][c] = BN(node_rep[n])[p-block] . w1[c] ----
__global__ __launch_bounds__(512) void node_gemm_k(
    const float* __restrict__ node_rep,
    const float* __restrict__ gam, const float* __restrict__ bet,
    const float* __restrict__ mean, const float* __restrict__ var,
    const float* __restrict__ w1, float* __restrict__ Hnode)
{
  __shared__ float a[FEA];
  const int n = blockIdx.x, p = blockIdx.y, c = threadIdx.x;
  if (c < FEA) {
    const int j = p * FEA + c;
    const float v = node_rep[n * FEA + c];
    a[c] = (v - mean[j]) * rsqrtf(var[j] + 1e-5f) * gam[j] + bet[j];
  }
  __syncthreads();
  const float* wrow = w1 + (size_t)c * 384 + p * FEA;
  float s = 0.f;
  #pragma unroll
  for (int k = 0; k < FEA; k += 4) {
    const float4 wv = *(const float4*)(wrow + k);
    s += a[k] * wv.x + a[k + 1] * wv.y + a[k + 2] * wv.z + a[k + 3] * wv.w;
  }
  Hnode[((size_t)p * NUM_NODE + n) * 512 + c] = s;
}

// ---------------- K4b: h1 = lrelu(gathered sum + b1), stored TILED for MFMA ----
// Tiled layout: elem (row,k) at ((row>>4)*64 + (k>>3))*128 + (row&15)*8 + (k&7).
__global__ __launch_bounds__(512) void gather_add_k(
    const float* __restrict__ Hnode, const int* __restrict__ index,
    const float* __restrict__ b1,
    unsigned short* __restrict__ h_hi, unsigned short* __restrict__ h_lo)
{
  const int r = blockIdx.x * 4 + (threadIdx.x >> 7);
  const int j = threadIdx.x & 127;           // float4 group, k0 = j*4
  const int i0 = index[r * 3 + 0], i1 = index[r * 3 + 1], i2 = index[r * 3 + 2];
  const float4 v0 = *(const float4*)(Hnode + ((size_t)0 * NUM_NODE + i0) * 512 + j * 4);
  const float4 v1 = *(const float4*)(Hnode + ((size_t)1 * NUM_NODE + i1) * 512 + j * 4);
  const float4 v2 = *(const float4*)(Hnode + ((size_t)2 * NUM_NODE + i2) * 512 + j * 4);
  const float4 bb = *(const float4*)(b1 + j * 4);
  float h[4];
  h[0] = v0.x + v1.x + v2.x + bb.x;
  h[1] = v0.y + v1.y + v2.y + bb.y;
  h[2] = v0.z + v1.z + v2.z + bb.z;
  h[3] = v0.w + v1.w + v2.w + bb.w;
  us4 hi4, lo4;
  #pragma unroll
  for (int u = 0; u < 4; ++u) {
    const float v = h[u] > 0.f ? h[u] : 0.5f * h[u];
    const unsigned short hh = f2bf_rtne(v);
    hi4[u] = hh;
    lo4[u] = f2bf_rtne(v - bf2f(hh));
  }
  const size_t o = ((size_t)(r >> 4) * 64 + (j >> 1)) * 128 + (r & 15) * 8 + (j & 1) * 4;
  *(us4*)(h_hi + o) = hi4;
  *(us4*)(h_lo + o) = lo4;
}

// ---------------- cvt: w2 -> split-bf16 in the same tiled layout ----------------
__global__ __launch_bounds__(256) void cvt_w2_tiled_k(
    const float* __restrict__ w2, unsigned short* __restrict__ hi,
    unsigned short* __restrict__ lo)
{
  const int i = blockIdx.x * 256 + threadIdx.x;    // [0, 256*64)
  const int col = i >> 6, oct = i & 63;
  const float* src = w2 + (size_t)col * 512 + oct * 8;
  us8 h8, l8;
  #pragma unroll
  for (int u = 0; u < 8; ++u) {
    const float v = src[u];
    const unsigned short hh = f2bf_rtne(v);
    h8[u] = hh;
    l8[u] = f2bf_rtne(v - bf2f(hh));
  }
  const size_t o = ((size_t)(col >> 4) * 64 + oct) * 128 + (col & 15) * 8;
  *(us8*)(hi + o) = h8;
  *(us8*)(lo + o) = l8;
}

// ---------------- K4c: hout = lrelu(h1 @ w2^T + b2); tiled coalesced loads ----
#define L2_LOAD(kk, b) do {                                    \
    const size_t kb = (size_t)(kk) * 512 + lane8;              \
    ah[b][0] = *(const bfrag*)(a_hi + tA0 + kb);               \
    ah[b][1] = *(const bfrag*)(a_hi + tA1 + kb);               \
    al[b][0] = *(const bfrag*)(a_lo + tA0 + kb);               \
    al[b][1] = *(const bfrag*)(a_lo + tA1 + kb);               \
    bh[b][0] = *(const bfrag*)(w_hi + tW0 + kb);               \
    bh[b][1] = *(const bfrag*)(w_hi + tW1 + kb);               \
    bl[b][0] = *(const bfrag*)(w_lo + tW0 + kb);               \
    bl[b][1] = *(const bfrag*)(w_lo + tW1 + kb);               \
  } while (0)

__global__ __launch_bounds__(512, 2) void lin2_k(
    const unsigned short* __restrict__ a_hi, const unsigned short* __restrict__ a_lo,
    const unsigned short* __restrict__ w_hi, const unsigned short* __restrict__ w_lo,
    const float* __restrict__ bias, float* __restrict__ C)
{
  const int lane = threadIdx.x & 63, wave = threadIdx.x >> 6;
  const int r16 = lane & 15, g = lane >> 4;
  const int wr = wave >> 1, wc = wave & 1;
  const int rowbase = blockIdx.y * 128 + wr * 32;
  const int colbase = blockIdx.x * 64 + wc * 32;
  const size_t lane8 = (size_t)lane * 8;
  const size_t tA0 = (size_t)(rowbase >> 4) * 8192, tA1 = tA0 + 8192;
  const size_t tW0 = (size_t)(colbase >> 4) * 8192, tW1 = tW0 + 8192;

  f32x4 acc00 = {0.f, 0.f, 0.f, 0.f}, acc01 = acc00, acc10 = acc00, acc11 = acc00;

  bfrag ah[2][2], al[2][2], bh[2][2], bl[2][2];
  L2_LOAD(0, 0);
  #pragma unroll
  for (int kk = 0; kk < 16; ++kk) {
    const int cur = kk & 1, nxt = cur ^ 1;
    if (kk < 15) L2_LOAD(kk + 1, nxt);
    acc00 = MFMA16(ah[cur][0], bh[cur][0], acc00);
    acc00 = MFMA16(ah[cur][0], bl[cur][0], acc00);
    acc00 = MFMA16(al[cur][0], bh[cur][0], acc00);
    acc01 = MFMA16(ah[cur][0], bh[cur][1], acc01);
    acc01 = MFMA16(ah[cur][0], bl[cur][1], acc01);
    acc01 = MFMA16(al[cur][0], bh[cur][1], acc01);
    acc10 = MFMA16(ah[cur][1], bh[cur][0], acc10);
    acc10 = MFMA16(ah[cur][1], bl[cur][0], acc10);
    acc10 = MFMA16(al[cur][1], bh[cur][0], acc10);
    acc11 = MFMA16(ah[cur][1], bh[cur][1], acc11);
    acc11 = MFMA16(ah[cur][1], bl[cur][1], acc11);
    acc11 = MFMA16(al[cur][1], bh[cur][1], acc11);
  }

  f32x4 av[2][2] = {{acc00, acc01}, {acc10, acc11}};
  #pragma unroll
  for (int t = 0; t < 2; ++t) {
    #pragma unroll
    for (int u = 0; u < 2; ++u) {
      const int col = colbase + u * 16 + r16;
      const float bv = bias[col];
      #pragma unroll
      for (int i = 0; i < 4; ++i) {
        float v = av[t][u][i] + bv;
        v = v > 0.f ? v : 0.5f * v;
        C[(size_t)(rowbase + t * 16 + g * 4 + i) * 256 + col] = v;
      }
    }
  }
}

// ---------------- K4d: out0 = sigmoid(h @ w3 + b3) ----------------
__global__ __launch_bounds__(256) void lin3_k(
    const float* __restrict__ H, const float* __restrict__ w3,
    const float* __restrict__ b3, float* __restrict__ out)
{
  const int row = blockIdx.x * 4 + (threadIdx.x >> 6);
  const int lane = threadIdx.x & 63;
  const float4 h = *(const float4*)(H + (size_t)row * 256 + lane * 4);
  const float4 w = *(const float4*)(w3 + lane * 4);
  float v = h.x * w.x + h.y * w.y + h.z * w.z + h.w * w.w;
  #pragma unroll
  for (int off = 32; off; off >>= 1) v += __shfl_down(v, off);
  if (lane == 0) out[row] = 1.f / (1.f + expf(-(v + b3[0])));
}

extern "C" void kernel_launch(void* const* d_in, const int* in_sizes, int n_in,
                              void* d_out, int out_size, void* d_ws, size_t ws_size,
                              hipStream_t stream) {
  const float* dth_cls  = (const float*)d_in[2];
  const float* dth_dc   = (const float*)d_in[3];
  const int*   he_node  = (const int*)d_in[4];
  const int*   he_edge  = (const int*)d_in[5];
  const int*   index    = (const int*)d_in[7];
  const float* dE       = (const float*)d_in[8];
  const float* cE       = (const float*)d_in[9];
  const float* node_proj= (const float*)d_in[10];
  const float* edge_proj= (const float*)d_in[11];
  const float* fc_w     = (const float*)d_in[12];
  const float* fc_b     = (const float*)d_in[13];
  const float* bn_g     = (const float*)d_in[14];
  const float* bn_b     = (const float*)d_in[15];
  const float* bn_m     = (const float*)d_in[16];
  const float* bn_v     = (const float*)d_in[17];
  const float* w1       = (const float*)d_in[18];
  const float* b1       = (const float*)d_in[19];
  const float* w2       = (const float*)d_in[20];
  const float* b2       = (const float*)d_in[21];
  const float* w3       = (const float*)d_in[22];
  const float* b3       = (const float*)d_in[23];

  float* out0 = (float*)d_out;
  float* hout = out0 + BATCH;                      // [8192,256] fp32, 2nd output

  float* ws = (float*)d_ws;
  float*          edge_group = ws + 10048;                      // -> 27968
  float*          node_rep   = ws + 28032;                      // -> 36992
  float*          Hnode      = ws + 37056;                      // 3*70*512 -> 144576
  unsigned short* w2_hi      = (unsigned short*)(ws + 144640);  // tiled, -> 210176
  unsigned short* w2_lo      = (unsigned short*)(ws + 210176);  // -> 275712
  unsigned short* h1_hi      = (unsigned short*)(ws + 275712);  // tiled, -> 2372864
  unsigned short* h1_lo      = (unsigned short*)(ws + 2372864); // -> 4470016 (17.9MB)
  // seg scratch aliased into h1 span (all consumed before gather_add writes h1):
  int*            sorted_off = (int*)(ws + 275712);             // -> 800000
  int*            hist_t     = (int*)(ws + 800000);             // 128*8960 -> 1946880
  int*            scan_t     = (int*)(ws + 1946880);            // -> 3093760
  int*            bucket_tot = (int*)(ws + 3093760);            // -> 3102720
  int*            bucket_base= (int*)(ws + 3102720);            // 8961 -> 3111681
  float*          partial    = ws + 3111688;                    // 627200 -> 3738888

  // w2 tiled split conversion (independent)
  cvt_w2_tiled_k<<<64, 256, 0, stream>>>(w2, w2_hi, w2_lo);

  // segment-mean pipeline, (seg,slice) counting sort
  hist_k<<<NBH2, 256, 0, stream>>>(he_node, he_edge, hist_t);
  col_scan_k<<<(NKEY + 255) / 256, 256, 0, stream>>>(hist_t, scan_t, bucket_tot);
  base_k<<<1, 1024, 0, stream>>>(bucket_tot, bucket_base);
  scatter_k<<<NBH2, 256, 0, stream>>>(he_node, he_edge, scan_t, bucket_base, sorted_off);
  seg_acc_k<<<NSEG * NSLICE / 4, 256, 0, stream>>>(dth_cls, dth_dc, sorted_off,
                                                   bucket_base, partial);
  seg_fin_edge_k<<<NSEG, 128, 0, stream>>>(partial, bucket_base, dE, cE, edge_group);
  node_rep_k<<<NUM_NODE, 128, 0, stream>>>(edge_group, dE, cE, node_proj, edge_proj,
                                           fc_w, fc_b, node_rep);

  // decoder layer 1: exact fp32 via 210-row table + coalesced gather-add (tiled out)
  node_gemm_k<<<dim3(NUM_NODE, 3), 512, 0, stream>>>(node_rep, bn_g, bn_b, bn_m, bn_v,
                                                     w1, Hnode);
  gather_add_k<<<BATCH / 4, 512, 0, stream>>>(Hnode, index, b1, h1_hi, h1_lo);

  // decoder layer 2 (split-bf16 MFMA, tiled operands) + head
  lin2_k<<<dim3(256 / 64, BATCH / 128), 512, 0, stream>>>(h1_hi, h1_lo, w2_hi, w2_lo,
                                                          b2, hout);
  lin3_k<<<BATCH / 4, 256, 0, stream>>>(hout, w3, b3, out0);
}